// Round 1
// baseline (150.970 us; speedup 1.0000x reference)
//
#include <hip/hip_runtime.h>
#include <hip/hip_bf16.h>

// out[e,i] = sum_j (e@W1+b1)[e, i*16+j] * h[e,j]  +  (e@W2+b2)[e,i]
// Reformulated as a single bf16 MFMA GEMM over K=576:
//   K [0,512):   P[e, d*16+j] = e[e,d]*h[e,j],  B[d*16+j, i] = W1[d, i*16+j]
//   K [512,544): P = e[e,d],                    B = W2[d,i]
//   K [544,560): P = h[e,j],                    B = b1[i*16+j]
//   K slot 560:  P = 1,                         B = b2[i]
// 18x mfma_f32_16x16x32_bf16 per 16-edge tile; D fragment = output directly.

using bf16x8 = __attribute__((ext_vector_type(8))) short;  // 8 bf16 (4 VGPRs)
using f32x4  = __attribute__((ext_vector_type(4))) float;

static __device__ __forceinline__ short f2bf(float x) {
    __hip_bfloat16 b = __float2bfloat16(x);
    union { __hip_bfloat16 b; short s; } u;
    u.b = b;
    return u.s;
}

__global__ void __launch_bounds__(256) msg_kernel(
    const float* __restrict__ hptr, const float* __restrict__ eptr,
    const float* __restrict__ W1,   const float* __restrict__ b1,
    const float* __restrict__ W2,   const float* __restrict__ b2,
    float* __restrict__ out, int E)
{
    const int lane = threadIdx.x & 63;
    const int g    = lane >> 4;        // 0..3 : K-group of the fragment
    const int r    = lane & 15;        // A row (edge-in-tile) == B/D col (output i)
    const int g2   = g >> 1;           // e-parity for main blocks
    const int gh   = (g & 1) * 8;      // h-half offset (j base)

    // ---- B fragments: edge-invariant, precompute into registers ----
    bf16x8 Bf[18];
    #pragma unroll
    for (int kk = 0; kk < 16; ++kk) {
        #pragma unroll
        for (int t = 0; t < 8; ++t) {
            const int gk = g * 8 + t;            // position within K-32 block
            const int d  = 2 * kk + (gk >> 4);
            const int j  = gk & 15;
            Bf[kk][t] = f2bf(W1[d * 256 + r * 16 + j]);
        }
    }
    #pragma unroll
    for (int t = 0; t < 8; ++t) {                // W2 block
        const int d = g * 8 + t;
        Bf[16][t] = f2bf(W2[d * 16 + r]);
    }
    #pragma unroll
    for (int t = 0; t < 8; ++t) {                // b1 / b2 block
        const int kq = g * 8 + t;
        float v = 0.0f;
        if (kq < 16)       v = b1[r * 16 + kq];
        else if (kq == 16) v = b2[r];
        Bf[17][t] = f2bf(v);
    }

    const int ntiles = (E + 15) >> 4;
    const int nwaves = (gridDim.x * blockDim.x) >> 6;
    const int wid    = (blockIdx.x * blockDim.x + threadIdx.x) >> 6;

    for (int tile = wid; tile < ntiles; tile += nwaves) {
        const int edge = tile * 16 + r;
        const int ce   = (edge < E) ? edge : (E - 1);

        // h-half this lane needs: j in [gh, gh+8)
        const float4* hp = (const float4*)(hptr + (size_t)ce * 16 + gh);
        const float4 h0 = hp[0];
        const float4 h1 = hp[1];
        const float hv[8] = {h0.x, h0.y, h0.z, h0.w, h1.x, h1.y, h1.z, h1.w};

        // e values for main blocks: d = 2*kk + g2 (parity-selected, static index)
        const float4* ep = (const float4*)(eptr + (size_t)ce * 32);
        float ev[16];
        #pragma unroll
        for (int q = 0; q < 8; ++q) {
            const float4 e4 = ep[q];
            ev[2 * q + 0] = g2 ? e4.y : e4.x;   // e[4q   + g2]
            ev[2 * q + 1] = g2 ? e4.w : e4.z;   // e[4q+2 + g2]
        }
        // e values for W2 block: d in [g*8, g*8+8)
        const float4* ep2 = (const float4*)(eptr + (size_t)ce * 32 + g * 8);
        const float4 ea = ep2[0];
        const float4 eb = ep2[1];
        const float ec[8] = {ea.x, ea.y, ea.z, ea.w, eb.x, eb.y, eb.z, eb.w};

        f32x4 acc = {0.0f, 0.0f, 0.0f, 0.0f};

        #pragma unroll
        for (int kk = 0; kk < 16; ++kk) {
            const float ed = ev[kk];
            bf16x8 a;
            #pragma unroll
            for (int t = 0; t < 8; ++t) a[t] = f2bf(ed * hv[t]);
            acc = __builtin_amdgcn_mfma_f32_16x16x32_bf16(a, Bf[kk], acc, 0, 0, 0);
        }
        {   // W2 block: P = e[e,d]
            bf16x8 a;
            #pragma unroll
            for (int t = 0; t < 8; ++t) a[t] = f2bf(ec[t]);
            acc = __builtin_amdgcn_mfma_f32_16x16x32_bf16(a, Bf[16], acc, 0, 0, 0);
        }
        {   // b1/b2 block: P = h[e,j] for k'<16, P=1 at k'=16
            bf16x8 a;
            #pragma unroll
            for (int t = 0; t < 8; ++t) {
                float v;
                if (g < 2) v = hv[t];
                else       v = (g == 2 && t == 0) ? 1.0f : 0.0f;
                a[t] = f2bf(v);
            }
            acc = __builtin_amdgcn_mfma_f32_16x16x32_bf16(a, Bf[17], acc, 0, 0, 0);
        }

        // D: col = lane&15 = i, row = g*4 + q = edge-in-tile
        const int rowbase = tile * 16 + g * 4;
        #pragma unroll
        for (int q = 0; q < 4; ++q) {
            const int row = rowbase + q;
            if (row < E) out[(size_t)row * 16 + r] = acc[q];
        }
    }
}

extern "C" void kernel_launch(void* const* d_in, const int* in_sizes, int n_in,
                              void* d_out, int out_size, void* d_ws, size_t ws_size,
                              hipStream_t stream) {
    const float* h  = (const float*)d_in[0];
    const float* e  = (const float*)d_in[1];
    const float* W1 = (const float*)d_in[2];
    const float* b1 = (const float*)d_in[3];
    const float* W2 = (const float*)d_in[4];
    const float* b2 = (const float*)d_in[5];
    float* out = (float*)d_out;

    const int E = in_sizes[0] / 16;   // h is [E,16]

    dim3 grid(2048), block(256);
    hipLaunchKernelGGL(msg_kernel, grid, block, 0, stream,
                       h, e, W1, b1, W2, b2, out, E);
}